// Round 2
// baseline (281.357 us; speedup 1.0000x reference)
//
#include <hip/hip_runtime.h>
#include <hip/hip_bf16.h>
#include <math.h>
#include <float.h>

// Problem constants (x: [8192,128] f32, n_images=2)
static constexpr int NN   = 8192;
static constexpr int DD   = 128;
static constexpr int PP   = 4096;              // persons
static constexpr int TILE = 128;
static constexpr int TT   = NN / TILE;         // 64 tiles per dim
static constexpr int NBLK = TT * (TT + 1) / 2; // 2080 upper-tri tile pairs
static constexpr int NC   = NBLK * 8;          // 8 candidates per block (top-2 per 64x64 quadrant)

struct Cand { float v; unsigned idx; };

using short8 = __attribute__((ext_vector_type(8))) short;
using f32x4  = __attribute__((ext_vector_type(4))) float;

__device__ __forceinline__ short bf16bits(float f) {
    __hip_bfloat16 h = __float2bfloat16(f);   // HW cvt (RNE) on gfx950
    return (short)__builtin_bit_cast(unsigned short, h);
}

// load 8 consecutive fp32, convert to packed bf16x8 fragment
__device__ __forceinline__ short8 cvt8(const float* __restrict__ p) {
    float4 f0 = *(const float4*)p;
    float4 f1 = *(const float4*)(p + 4);
    short8 r;
    r[0] = bf16bits(f0.x); r[1] = bf16bits(f0.y);
    r[2] = bf16bits(f0.z); r[3] = bf16bits(f0.w);
    r[4] = bf16bits(f1.x); r[5] = bf16bits(f1.y);
    r[6] = bf16bits(f1.z); r[7] = bf16bits(f1.w);
    return r;
}

__device__ __forceinline__ void push1(float& v1, unsigned& i1, float& v2, unsigned& i2,
                                      float w, unsigned j) {
    if (w > v1) { v2 = v1; i2 = i1; v1 = w; i1 = j; }
    else if (w > v2) { v2 = w; i2 = j; }
}

__device__ __forceinline__ void merge2(float& v1, unsigned& i1, float& v2, unsigned& i2,
                                       float w1, unsigned j1, float w2, unsigned j2) {
    if (w1 > v1) {
        float nv2; unsigned ni2;
        if (v1 >= w2) { nv2 = v1; ni2 = i1; } else { nv2 = w2; ni2 = j2; }
        v1 = w1; i1 = j1; v2 = nv2; i2 = ni2;
    } else if (w1 > v2) {
        v2 = w1; i2 = j1;
    }
}

// ---- kernel 1: sim_self[p] = dot(x[p], x[p+1]) in double ----
__global__ void k_simself(const float* __restrict__ x, double* __restrict__ ss) {
    int p = blockIdx.x * blockDim.x + threadIdx.x;
    if (p >= PP) return;
    const float* a = x + (size_t)p * DD;
    const float* b = a + DD;
    double s0 = 0.0, s1 = 0.0;
    #pragma unroll 8
    for (int k = 0; k < DD; k += 2) {
        s0 += (double)a[k] * (double)b[k];
        s1 += (double)a[k + 1] * (double)b[k + 1];
    }
    ss[p] = s0 + s1;
}

// ---- kernel 2: MFMA-based approximate top-2 per 64x64 quadrant of the
// upper triangle of G = x x^T (bf16 inputs, fp32 accumulate) ----
__global__ __launch_bounds__(256) void k_top2(const float* __restrict__ x,
                                              Cand* __restrict__ cands) {
    // decode linear block id -> (ti, tj), ti <= tj
    int rem = blockIdx.x;
    int ti = 0;
    while (rem >= TT - ti) { rem -= (TT - ti); ++ti; }
    int tj = ti + rem;

    const int tid  = threadIdx.x;
    const int wv   = tid >> 6;      // wave 0..3
    const int lane = tid & 63;
    const int wm   = wv >> 1;       // wave row 0..1
    const int wn   = wv & 1;        // wave col 0..1
    const int quad = lane >> 4;     // 0..3
    const int r16  = lane & 15;     // 0..15

    const int ibase = ti * TILE + wm * 64;
    const int jbase = tj * TILE + wn * 64;

    f32x4 acc[4][4];
    #pragma unroll
    for (int mi = 0; mi < 4; ++mi)
        #pragma unroll
        for (int nj = 0; nj < 4; ++nj)
            acc[mi][nj] = (f32x4){0.f, 0.f, 0.f, 0.f};

    // A fragment: lane holds x[ibase + mi*16 + r16][quad*8 + j + s*32], j=0..7
    // B fragment: lane holds x[jbase + nj*16 + r16][quad*8 + j + s*32]  (B = x^T)
    const float* Abase = x + (size_t)(ibase + r16) * DD + quad * 8;
    const float* Bbase = x + (size_t)(jbase + r16) * DD + quad * 8;

    #pragma unroll
    for (int s = 0; s < 4; ++s) {
        short8 af[4], bf[4];
        #pragma unroll
        for (int mi = 0; mi < 4; ++mi) {
            af[mi] = cvt8(Abase + (size_t)mi * 16 * DD + s * 32);
            bf[mi] = cvt8(Bbase + (size_t)mi * 16 * DD + s * 32);
        }
        #pragma unroll
        for (int mi = 0; mi < 4; ++mi)
            #pragma unroll
            for (int nj = 0; nj < 4; ++nj)
                acc[mi][nj] = __builtin_amdgcn_mfma_f32_16x16x32_bf16(
                    af[mi], bf[nj], acc[mi][nj], 0, 0, 0);
    }

    // epilogue: per-lane top-2 over the 64 accumulator values (i<j only)
    // C/D layout: col = lane&15, row = (lane>>4)*4 + reg  [m89/m91 verified]
    float v1 = -INFINITY, v2 = -INFINITY;
    unsigned i1 = 0, i2 = 0;
    #pragma unroll
    for (int mi = 0; mi < 4; ++mi) {
        #pragma unroll
        for (int nj = 0; nj < 4; ++nj) {
            int gj = jbase + nj * 16 + r16;
            #pragma unroll
            for (int reg = 0; reg < 4; ++reg) {
                int gi = ibase + mi * 16 + quad * 4 + reg;
                if (gi < gj) {
                    unsigned idx = (unsigned)(gi * NN + gj);
                    push1(v1, i1, v2, i2, acc[mi][nj][reg], idx);
                }
            }
        }
    }

    // wave-level (64 lane) top-2 reduction
    #pragma unroll
    for (int off = 32; off >= 1; off >>= 1) {
        float    w1 = __shfl_down(v1, off);
        unsigned j1 = (unsigned)__shfl_down((int)i1, off);
        float    w2 = __shfl_down(v2, off);
        unsigned j2 = (unsigned)__shfl_down((int)i2, off);
        merge2(v1, i1, v2, i2, w1, j1, w2, j2);
    }
    if (lane == 0) {
        cands[blockIdx.x * 8 + wv * 2]     = {v1, i1};
        cands[blockIdx.x * 8 + wv * 2 + 1] = {v2, i2};
    }
}

// ---- kernel 3: approx top-2 -> exact recheck (double) -> final mean ----
__global__ __launch_bounds__(256) void k_final(const float* __restrict__ x,
                                               const double* __restrict__ ss,
                                               const Cand* __restrict__ cands,
                                               float* __restrict__ out) {
    __shared__ float redv[8];
    __shared__ float s_thresh;
    __shared__ int cnt;
    __shared__ unsigned qidx[128];
    __shared__ double qex[128];
    __shared__ double sd1, sd2;
    __shared__ unsigned stopi;
    __shared__ double sacc[256];

    const int tid  = threadIdx.x;
    const int wv   = tid >> 6;
    const int lane = tid & 63;
    if (tid == 0) cnt = 0;

    // Phase A: approx global top-2 VALUES
    float v1 = -INFINITY, v2 = -INFINITY;
    for (int e = tid; e < NC; e += 256) {
        float v = cands[e].v;
        if (v > v1) { v2 = v1; v1 = v; }
        else if (v > v2) v2 = v;
    }
    #pragma unroll
    for (int off = 32; off >= 1; off >>= 1) {
        float w1 = __shfl_down(v1, off);
        float w2 = __shfl_down(v2, off);
        if (w1 > v1) { v2 = (v1 >= w2) ? v1 : w2; v1 = w1; }
        else if (w1 > v2) v2 = w1;
    }
    if (lane == 0) { redv[wv * 2] = v1; redv[wv * 2 + 1] = v2; }
    __syncthreads();
    if (tid == 0) {
        float a1 = -INFINITY, a2 = -INFINITY;
        for (int e = 0; e < 8; ++e) {
            float v = redv[e];
            if (v > a1) { a2 = a1; a1 = v; }
            else if (v > a2) a2 = v;
        }
        s_thresh = a2 - 1.0f;   // margin >> bf16 dot-product error bound (~0.1)
    }
    __syncthreads();
    const float thresh = s_thresh;

    // Phase B: gather all candidates within margin of approx top-2
    for (int e = tid; e < NC; e += 256) {
        if (cands[e].v >= thresh) {
            int k = atomicAdd(&cnt, 1);
            if (k < 128) qidx[k] = cands[e].idx;
        }
    }
    __syncthreads();
    const int n = cnt < 128 ? cnt : 128;

    // Phase C: exact double dot for each qualifying candidate (one wave each)
    for (int c = wv; c < n; c += 4) {
        unsigned idx = qidx[c];
        unsigned gi = idx >> 13;       // / 8192
        unsigned gj = idx & 8191;
        const float* pa = x + (size_t)gi * DD;
        const float* pb = x + (size_t)gj * DD;
        double s = (double)pa[lane] * (double)pb[lane]
                 + (double)pa[lane + 64] * (double)pb[lane + 64];
        #pragma unroll
        for (int off = 32; off >= 1; off >>= 1) s += __shfl_down(s, off);
        if (lane == 0) qex[c] = s;
    }
    __syncthreads();

    // Phase D: exact top-2 over rechecked candidates
    if (tid == 0) {
        double d1 = -DBL_MAX, d2 = -DBL_MAX;
        unsigned bi = 0;
        for (int c = 0; c < n; ++c) {
            double v = qex[c];
            if (v > d1) { d2 = d1; d1 = v; bi = qidx[c]; }
            else if (v > d2) d2 = v;
        }
        sd1 = d1; sd2 = d2; stopi = bi;
    }
    __syncthreads();

    const double top1 = sd1, top2 = sd2;
    const unsigned topi = stopi;

    // Phase E: mean(sim_oth / sim_self)
    double acc = 0.0;
    for (int p = tid; p < PP; p += 256) {
        unsigned selfidx = (unsigned)(p * NN + p + 1);
        double so = (topi == selfidx) ? top2 : top1;
        acc += so / ss[p];
    }
    sacc[tid] = acc;
    __syncthreads();
    for (int s = 128; s >= 1; s >>= 1) {
        if (tid < s) sacc[tid] += sacc[tid + s];
        __syncthreads();
    }
    if (tid == 0) out[0] = (float)(sacc[0] / (double)PP);
}

extern "C" void kernel_launch(void* const* d_in, const int* in_sizes, int n_in,
                              void* d_out, int out_size, void* d_ws, size_t ws_size,
                              hipStream_t stream) {
    (void)in_sizes; (void)n_in; (void)out_size; (void)ws_size;
    const float* x = (const float*)d_in[0];
    float* out = (float*)d_out;

    double* ss  = (double*)d_ws;                                   // PP doubles
    Cand* cands = (Cand*)((char*)d_ws + PP * sizeof(double));      // NC Cands

    k_simself<<<PP / 256, 256, 0, stream>>>(x, ss);
    k_top2<<<NBLK, 256, 0, stream>>>(x, cands);
    k_final<<<1, 256, 0, stream>>>(x, ss, cands, out);
}

// Round 3
// 206.164 us; speedup vs baseline: 1.3647x; 1.3647x over previous
//
#include <hip/hip_runtime.h>
#include <hip/hip_bf16.h>
#include <math.h>
#include <float.h>

// Problem constants (x: [8192,128] f32, n_images=2)
static constexpr int NN    = 8192;
static constexpr int DD    = 128;
static constexpr int PP    = 4096;              // persons
static constexpr int TILE  = 128;
static constexpr int TT    = NN / TILE;         // 64 tiles per dim
static constexpr int NBLK  = TT * (TT + 1) / 2; // 2080 upper-tri tile pairs
static constexpr int SSBLK = 64;                // extra blocks doing sim_self
static constexpr int NC    = NBLK * 2;          // 2 candidates per tile block

struct Cand { float v; unsigned idx; };

using short8 = __attribute__((ext_vector_type(8))) short;
using f32x4  = __attribute__((ext_vector_type(4))) float;

__device__ __forceinline__ unsigned pk2(float lo, float hi) {
    unsigned a = (unsigned)__builtin_bit_cast(unsigned short, __float2bfloat16(lo));
    unsigned b = (unsigned)__builtin_bit_cast(unsigned short, __float2bfloat16(hi));
    return a | (b << 16);
}

__device__ __forceinline__ void push1(float& v1, unsigned& i1, float& v2, unsigned& i2,
                                      float w, unsigned j) {
    if (w > v1) { v2 = v1; i2 = i1; v1 = w; i1 = j; }
    else if (w > v2) { v2 = w; i2 = j; }
}

__device__ __forceinline__ void merge2(float& v1, unsigned& i1, float& v2, unsigned& i2,
                                       float w1, unsigned j1, float w2, unsigned j2) {
    if (w1 > v1) {
        float nv2; unsigned ni2;
        if (v1 >= w2) { nv2 = v1; ni2 = i1; } else { nv2 = w2; ni2 = j2; }
        v1 = w1; i1 = j1; v2 = nv2; i2 = ni2;
    } else if (w1 > v2) {
        v2 = w1; i2 = j1;
    }
}

// ---- kernel 1: MFMA top-2 over upper triangle of G = x x^T (LDS-staged,
// bf16 inputs converted in-flight, XOR-swizzled LDS) + fused sim_self ----
__global__ __launch_bounds__(256) void k_top2(const float* __restrict__ x,
                                              Cand* __restrict__ cands,
                                              double* __restrict__ ss) {
    __shared__ uint4 As4[TILE * 16];   // 128 rows x 16 chunks(16B bf16) = 32 KB
    __shared__ uint4 Bs4[TILE * 16];   // 32 KB
    __shared__ float sv1[4], sv2[4];
    __shared__ unsigned si1[4], si2[4];

    const int tid  = threadIdx.x;
    const int wv   = tid >> 6;      // wave 0..3
    const int lane = tid & 63;

    // ---- tail blocks: sim_self[p] = dot(x[p], x[p+1]) in double ----
    if (blockIdx.x >= NBLK) {
        int b = blockIdx.x - NBLK;          // 0..63
        #pragma unroll 4
        for (int u = 0; u < 16; ++u) {
            int p = b * 64 + wv * 16 + u;   // 0..4095
            const float* a  = x + (size_t)p * DD;
            const float* bb = a + DD;
            double s = (double)a[lane] * (double)bb[lane]
                     + (double)a[lane + 64] * (double)bb[lane + 64];
            #pragma unroll
            for (int off = 32; off >= 1; off >>= 1) s += __shfl_down(s, off);
            if (lane == 0) ss[p] = s;
        }
        return;
    }

    // decode linear block id -> (ti, tj), ti <= tj
    int rem = blockIdx.x;
    int ti = 0;
    while (rem >= TT - ti) { rem -= (TT - ti); ++ti; }
    int tj = ti + rem;

    // ---- stage both tiles: fp32 global -> bf16 LDS, swizzled ----
    #pragma unroll
    for (int it = 0; it < 8; ++it) {
        int g   = tid + 256 * it;   // chunk id 0..2047
        int row = g >> 4;           // 0..127
        int c   = g & 15;           // 16B-chunk within row
        int pos = row * 16 + (c ^ (row & 7));
        const float* sa = x + (size_t)(ti * TILE + row) * DD + c * 8;
        float4 a0 = *(const float4*)sa;
        float4 a1 = *(const float4*)(sa + 4);
        uint4 pa = {pk2(a0.x, a0.y), pk2(a0.z, a0.w), pk2(a1.x, a1.y), pk2(a1.z, a1.w)};
        As4[pos] = pa;
        const float* sb = x + (size_t)(tj * TILE + row) * DD + c * 8;
        float4 b0 = *(const float4*)sb;
        float4 b1 = *(const float4*)(sb + 4);
        uint4 pb = {pk2(b0.x, b0.y), pk2(b0.z, b0.w), pk2(b1.x, b1.y), pk2(b1.z, b1.w)};
        Bs4[pos] = pb;
    }
    __syncthreads();

    const int wm   = wv >> 1;       // wave row 0..1
    const int wn   = wv & 1;        // wave col 0..1
    const int quad = lane >> 4;     // 0..3
    const int r16  = lane & 15;     // 0..15
    const int swz  = r16 & 7;

    f32x4 acc[4][4];
    #pragma unroll
    for (int mi = 0; mi < 4; ++mi)
        #pragma unroll
        for (int nj = 0; nj < 4; ++nj)
            acc[mi][nj] = (f32x4){0.f, 0.f, 0.f, 0.f};

    #pragma unroll
    for (int s = 0; s < 4; ++s) {
        const int cc = (quad + 4 * s) ^ swz;
        short8 af[4], bfr[4];
        #pragma unroll
        for (int mi = 0; mi < 4; ++mi) {
            af[mi]  = __builtin_bit_cast(short8, As4[(wm * 64 + mi * 16 + r16) * 16 + cc]);
            bfr[mi] = __builtin_bit_cast(short8, Bs4[(wn * 64 + mi * 16 + r16) * 16 + cc]);
        }
        #pragma unroll
        for (int mi = 0; mi < 4; ++mi)
            #pragma unroll
            for (int nj = 0; nj < 4; ++nj)
                acc[mi][nj] = __builtin_amdgcn_mfma_f32_16x16x32_bf16(
                    af[mi], bfr[nj], acc[mi][nj], 0, 0, 0);
    }

    // ---- epilogue: per-lane top-2 over valid (i<j) ----
    // C/D layout: col = lane&15, row = (lane>>4)*4 + reg  [verified round 2]
    const int ibase = ti * TILE + wm * 64;
    const int jbase = tj * TILE + wn * 64;
    float v1 = -INFINITY, v2 = -INFINITY;
    unsigned i1 = 0, i2 = 0;
    #pragma unroll
    for (int mi = 0; mi < 4; ++mi) {
        #pragma unroll
        for (int nj = 0; nj < 4; ++nj) {
            int gj = jbase + nj * 16 + r16;
            #pragma unroll
            for (int reg = 0; reg < 4; ++reg) {
                int gi = ibase + mi * 16 + quad * 4 + reg;
                if (gi < gj) {
                    unsigned idx = (unsigned)(gi * NN + gj);
                    push1(v1, i1, v2, i2, acc[mi][nj][reg], idx);
                }
            }
        }
    }

    // wave-level top-2 reduction
    #pragma unroll
    for (int off = 32; off >= 1; off >>= 1) {
        float    w1 = __shfl_down(v1, off);
        unsigned j1 = (unsigned)__shfl_down((int)i1, off);
        float    w2 = __shfl_down(v2, off);
        unsigned j2 = (unsigned)__shfl_down((int)i2, off);
        merge2(v1, i1, v2, i2, w1, j1, w2, j2);
    }
    if (lane == 0) { sv1[wv] = v1; si1[wv] = i1; sv2[wv] = v2; si2[wv] = i2; }
    __syncthreads();
    if (tid == 0) {
        for (int w = 1; w < 4; ++w)
            merge2(v1, i1, v2, i2, sv1[w], si1[w], sv2[w], si2[w]);
        cands[blockIdx.x * 2]     = {v1, i1};
        cands[blockIdx.x * 2 + 1] = {v2, i2};
    }
}

// ---- kernel 2: approx top-2 -> exact recheck (double) -> final mean ----
__global__ __launch_bounds__(256) void k_final(const float* __restrict__ x,
                                               const double* __restrict__ ss,
                                               const Cand* __restrict__ cands,
                                               float* __restrict__ out) {
    __shared__ float redv[8];
    __shared__ float s_thresh;
    __shared__ int cnt;
    __shared__ unsigned qidx[128];
    __shared__ double qex[128];
    __shared__ double sd1, sd2;
    __shared__ unsigned stopi;
    __shared__ double sacc[256];

    const int tid  = threadIdx.x;
    const int wv   = tid >> 6;
    const int lane = tid & 63;
    if (tid == 0) cnt = 0;

    // Phase A: approx global top-2 VALUES
    float v1 = -INFINITY, v2 = -INFINITY;
    for (int e = tid; e < NC; e += 256) {
        float v = cands[e].v;
        if (v > v1) { v2 = v1; v1 = v; }
        else if (v > v2) v2 = v;
    }
    #pragma unroll
    for (int off = 32; off >= 1; off >>= 1) {
        float w1 = __shfl_down(v1, off);
        float w2 = __shfl_down(v2, off);
        if (w1 > v1) { v2 = (v1 >= w2) ? v1 : w2; v1 = w1; }
        else if (w1 > v2) v2 = w1;
    }
    if (lane == 0) { redv[wv * 2] = v1; redv[wv * 2 + 1] = v2; }
    __syncthreads();
    if (tid == 0) {
        float a1 = -INFINITY, a2 = -INFINITY;
        for (int e = 0; e < 8; ++e) {
            float v = redv[e];
            if (v > a1) { a2 = a1; a1 = v; }
            else if (v > a2) a2 = v;
        }
        s_thresh = a2 - 1.0f;   // margin >> bf16 dot-product error bound (~0.1)
    }
    __syncthreads();
    const float thresh = s_thresh;

    // Phase B: gather all candidates within margin of approx top-2
    for (int e = tid; e < NC; e += 256) {
        if (cands[e].v >= thresh) {
            int k = atomicAdd(&cnt, 1);
            if (k < 128) qidx[k] = cands[e].idx;
        }
    }
    __syncthreads();
    const int n = cnt < 128 ? cnt : 128;

    // Phase C: exact double dot for each qualifying candidate (one wave each)
    for (int c = wv; c < n; c += 4) {
        unsigned idx = qidx[c];
        unsigned gi = idx >> 13;       // / 8192
        unsigned gj = idx & 8191;
        const float* pa = x + (size_t)gi * DD;
        const float* pb = x + (size_t)gj * DD;
        double s = (double)pa[lane] * (double)pb[lane]
                 + (double)pa[lane + 64] * (double)pb[lane + 64];
        #pragma unroll
        for (int off = 32; off >= 1; off >>= 1) s += __shfl_down(s, off);
        if (lane == 0) qex[c] = s;
    }
    __syncthreads();

    // Phase D: exact top-2 over rechecked candidates
    if (tid == 0) {
        double d1 = -DBL_MAX, d2 = -DBL_MAX;
        unsigned bi = 0;
        for (int c = 0; c < n; ++c) {
            double v = qex[c];
            if (v > d1) { d2 = d1; d1 = v; bi = qidx[c]; }
            else if (v > d2) d2 = v;
        }
        sd1 = d1; sd2 = d2; stopi = bi;
    }
    __syncthreads();

    const double top1 = sd1, top2 = sd2;
    const unsigned topi = stopi;

    // Phase E: mean(sim_oth / sim_self)
    double acc = 0.0;
    for (int p = tid; p < PP; p += 256) {
        unsigned selfidx = (unsigned)(p * NN + p + 1);
        double so = (topi == selfidx) ? top2 : top1;
        acc += so / ss[p];
    }
    sacc[tid] = acc;
    __syncthreads();
    for (int s = 128; s >= 1; s >>= 1) {
        if (tid < s) sacc[tid] += sacc[tid + s];
        __syncthreads();
    }
    if (tid == 0) out[0] = (float)(sacc[0] / (double)PP);
}

extern "C" void kernel_launch(void* const* d_in, const int* in_sizes, int n_in,
                              void* d_out, int out_size, void* d_ws, size_t ws_size,
                              hipStream_t stream) {
    (void)in_sizes; (void)n_in; (void)out_size; (void)ws_size;
    const float* x = (const float*)d_in[0];
    float* out = (float*)d_out;

    double* ss  = (double*)d_ws;                               // PP doubles
    Cand* cands = (Cand*)((char*)d_ws + PP * sizeof(double));  // NC Cands

    k_top2<<<NBLK + SSBLK, 256, 0, stream>>>(x, cands, ss);
    k_final<<<1, 256, 0, stream>>>(x, ss, cands, out);
}

// Round 4
// 174.927 us; speedup vs baseline: 1.6084x; 1.1786x over previous
//
#include <hip/hip_runtime.h>
#include <hip/hip_bf16.h>
#include <math.h>
#include <float.h>

// Problem constants (x: [8192,128] f32, n_images=2)
static constexpr int NN    = 8192;
static constexpr int DD    = 128;
static constexpr int PP    = 4096;              // persons
static constexpr int TILE  = 128;
static constexpr int TT    = NN / TILE;         // 64 tiles per dim
static constexpr int NBLK  = TT * (TT + 1) / 2; // 2080 upper-tri tile pairs
static constexpr int NC    = NBLK * 2;          // 2 candidates per tile block
static constexpr int GRP   = 1088;              // 1024B data + 64B pad per 8-row group
static constexpr int TLDS  = 16 * GRP;          // 17408 B per 128x64 bf16 tile

struct Cand { float v; unsigned idx; };

using short8 = __attribute__((ext_vector_type(8))) short;
using f32x4  = __attribute__((ext_vector_type(4))) float;

typedef const __attribute__((address_space(1))) unsigned int* gas_uint;
typedef __attribute__((address_space(3))) unsigned int* las_uint;

// async 16B/lane global->LDS DMA. LDS dest = wave-uniform base + lane*16.
// Global address may vary per lane (gather). [m03/m97/m104]
__device__ __forceinline__ void dma16(const void* g, const void* l) {
    __builtin_amdgcn_global_load_lds(
        (gas_uint)(unsigned long long)g,
        (las_uint)(unsigned)(unsigned long long)l, 16, 0, 0);
}

__device__ __forceinline__ unsigned pk2(float lo, float hi) {
    unsigned a = (unsigned)__builtin_bit_cast(unsigned short, __float2bfloat16(lo));
    unsigned b = (unsigned)__builtin_bit_cast(unsigned short, __float2bfloat16(hi));
    return a | (b << 16);
}

__device__ __forceinline__ void push1(float& v1, unsigned& i1, float& v2, unsigned& i2,
                                      float w, unsigned j) {
    if (w > v1) { v2 = v1; i2 = i1; v1 = w; i1 = j; }
    else if (w > v2) { v2 = w; i2 = j; }
}

__device__ __forceinline__ void merge2(float& v1, unsigned& i1, float& v2, unsigned& i2,
                                       float w1, unsigned j1, float w2, unsigned j2) {
    if (w1 > v1) {
        float nv2; unsigned ni2;
        if (v1 >= w2) { nv2 = v1; ni2 = i1; } else { nv2 = w2; ni2 = j2; }
        v1 = w1; i1 = j1; v2 = nv2; i2 = ni2;
    } else if (w1 > v2) {
        v2 = w1; i2 = j1;
    }
}

// ---- kernel 0: x -> bf16 copy (once) + sim_self in double ----
__global__ __launch_bounds__(256) void k_prep(const float* __restrict__ x,
                                              unsigned short* __restrict__ xb,
                                              double* __restrict__ ss) {
    const int tid = threadIdx.x;
    if (blockIdx.x < 256) {
        // 65536 chunks x 16 floats -> 16 bf16
        int chunk = blockIdx.x * 256 + tid;
        const float4* s = (const float4*)(x + (size_t)chunk * 16);
        float4 f0 = s[0], f1 = s[1], f2 = s[2], f3 = s[3];
        uint4 o0 = {pk2(f0.x, f0.y), pk2(f0.z, f0.w), pk2(f1.x, f1.y), pk2(f1.z, f1.w)};
        uint4 o1 = {pk2(f2.x, f2.y), pk2(f2.z, f2.w), pk2(f3.x, f3.y), pk2(f3.z, f3.w)};
        uint4* d = (uint4*)(xb + (size_t)chunk * 16);
        d[0] = o0; d[1] = o1;
    } else {
        // 64 blocks: sim_self[p] = dot(x[p], x[p+1]) in double, wave per person
        int b = blockIdx.x - 256;          // 0..63
        const int wv = tid >> 6, lane = tid & 63;
        #pragma unroll 4
        for (int u = 0; u < 16; ++u) {
            int p = b * 64 + wv * 16 + u;  // 0..4095
            const float* a  = x + (size_t)p * DD;
            const float* bb = a + DD;
            double s = (double)a[lane] * (double)bb[lane]
                     + (double)a[lane + 64] * (double)bb[lane + 64];
            #pragma unroll
            for (int off = 32; off >= 1; off >>= 1) s += __shfl_down(s, off);
            if (lane == 0) ss[p] = s;
        }
    }
}

// ---- kernel 1: MFMA top-2 over upper triangle of G = xb xb^T.
// global_load_lds staging (16B), padded-group LDS layout, BK=64 two phases ----
__global__ __launch_bounds__(256, 4) void k_top2(const unsigned short* __restrict__ xb,
                                                 Cand* __restrict__ cands) {
    __shared__ __align__(16) char AsB[TLDS];
    __shared__ __align__(16) char BsB[TLDS];
    __shared__ float sv1[4], sv2[4];
    __shared__ unsigned si1[4], si2[4];

    const int tid  = threadIdx.x;
    const int wv   = tid >> 6;      // wave 0..3
    const int lane = tid & 63;

    // decode linear block id -> (ti, tj), ti <= tj
    int rem = blockIdx.x;
    int ti = 0;
    while (rem >= TT - ti) { rem -= (TT - ti); ++ti; }
    int tj = ti + rem;

    const int wm   = wv >> 1;       // wave row 0..1
    const int wn   = wv & 1;        // wave col 0..1
    const int quad = lane >> 4;     // 0..3
    const int r16  = lane & 15;     // 0..15

    // DMA lane mapping: 1024B = 8 rows x 128B (64 bf16 cols)
    const int grow = lane >> 3;         // row within group 0..7
    const int gcol = (lane & 7) * 8;    // col (elements) within 64-slice

    f32x4 acc[4][4];
    #pragma unroll
    for (int mi = 0; mi < 4; ++mi)
        #pragma unroll
        for (int nj = 0; nj < 4; ++nj)
            acc[mi][nj] = (f32x4){0.f, 0.f, 0.f, 0.f};

    #pragma unroll
    for (int p = 0; p < 2; ++p) {
        const int kk = p * 64;
        if (p) __syncthreads();   // protect LDS reuse across phases

        // stage: each wave DMAs 4 groups of A and 4 of B (8 instr/wave)
        #pragma unroll
        for (int t = 0; t < 4; ++t) {
            int g = wv * 4 + t;   // 0..15
            const unsigned short* ga =
                xb + (size_t)(ti * TILE + g * 8 + grow) * DD + kk + gcol;
            dma16(ga, AsB + g * GRP);
            const unsigned short* gb =
                xb + (size_t)(tj * TILE + g * 8 + grow) * DD + kk + gcol;
            dma16(gb, BsB + g * GRP);
        }
        __syncthreads();          // drains vmcnt (DMA complete)

        #pragma unroll
        for (int s = 0; s < 2; ++s) {
            const int cc = quad + 4 * s;   // k-chunk 0..7 within 64-slice
            short8 af[4], bfr[4];
            #pragma unroll
            for (int mi = 0; mi < 4; ++mi) {
                int ra = wm * 64 + mi * 16 + r16;
                af[mi] = *(const short8*)(AsB + (ra >> 3) * GRP + (ra & 7) * 128 + cc * 16);
                int rb = wn * 64 + mi * 16 + r16;
                bfr[mi] = *(const short8*)(BsB + (rb >> 3) * GRP + (rb & 7) * 128 + cc * 16);
            }
            #pragma unroll
            for (int mi = 0; mi < 4; ++mi)
                #pragma unroll
                for (int nj = 0; nj < 4; ++nj)
                    acc[mi][nj] = __builtin_amdgcn_mfma_f32_16x16x32_bf16(
                        af[mi], bfr[nj], acc[mi][nj], 0, 0, 0);
        }
    }

    // ---- epilogue: per-lane top-2 over valid (i<j) ----
    // C/D layout: col = lane&15, row = (lane>>4)*4 + reg  [verified r2/r3]
    const int ibase = ti * TILE + wm * 64;
    const int jbase = tj * TILE + wn * 64;
    float v1 = -INFINITY, v2 = -INFINITY;
    unsigned i1 = 0, i2 = 0;
    #pragma unroll
    for (int mi = 0; mi < 4; ++mi) {
        #pragma unroll
        for (int nj = 0; nj < 4; ++nj) {
            int gj = jbase + nj * 16 + r16;
            #pragma unroll
            for (int reg = 0; reg < 4; ++reg) {
                int gi = ibase + mi * 16 + quad * 4 + reg;
                if (gi < gj) {
                    unsigned idx = (unsigned)(gi * NN + gj);
                    push1(v1, i1, v2, i2, acc[mi][nj][reg], idx);
                }
            }
        }
    }

    #pragma unroll
    for (int off = 32; off >= 1; off >>= 1) {
        float    w1 = __shfl_down(v1, off);
        unsigned j1 = (unsigned)__shfl_down((int)i1, off);
        float    w2 = __shfl_down(v2, off);
        unsigned j2 = (unsigned)__shfl_down((int)i2, off);
        merge2(v1, i1, v2, i2, w1, j1, w2, j2);
    }
    if (lane == 0) { sv1[wv] = v1; si1[wv] = i1; sv2[wv] = v2; si2[wv] = i2; }
    __syncthreads();
    if (tid == 0) {
        for (int w = 1; w < 4; ++w)
            merge2(v1, i1, v2, i2, sv1[w], si1[w], sv2[w], si2[w]);
        cands[blockIdx.x * 2]     = {v1, i1};
        cands[blockIdx.x * 2 + 1] = {v2, i2};
    }
}

// ---- kernel 2: approx top-2 -> exact recheck (double) -> final mean ----
__global__ __launch_bounds__(256) void k_final(const float* __restrict__ x,
                                               const double* __restrict__ ss,
                                               const Cand* __restrict__ cands,
                                               float* __restrict__ out) {
    __shared__ float redv[8];
    __shared__ float s_thresh;
    __shared__ int cnt;
    __shared__ unsigned qidx[128];
    __shared__ double qex[128];
    __shared__ double sd1, sd2;
    __shared__ unsigned stopi;
    __shared__ double sacc[256];

    const int tid  = threadIdx.x;
    const int wv   = tid >> 6;
    const int lane = tid & 63;
    if (tid == 0) cnt = 0;

    // Phase A: approx global top-2 VALUES
    float v1 = -INFINITY, v2 = -INFINITY;
    for (int e = tid; e < NC; e += 256) {
        float v = cands[e].v;
        if (v > v1) { v2 = v1; v1 = v; }
        else if (v > v2) v2 = v;
    }
    #pragma unroll
    for (int off = 32; off >= 1; off >>= 1) {
        float w1 = __shfl_down(v1, off);
        float w2 = __shfl_down(v2, off);
        if (w1 > v1) { v2 = (v1 >= w2) ? v1 : w2; v1 = w1; }
        else if (w1 > v2) v2 = w1;
    }
    if (lane == 0) { redv[wv * 2] = v1; redv[wv * 2 + 1] = v2; }
    __syncthreads();
    if (tid == 0) {
        float a1 = -INFINITY, a2 = -INFINITY;
        for (int e = 0; e < 8; ++e) {
            float v = redv[e];
            if (v > a1) { a2 = a1; a1 = v; }
            else if (v > a2) a2 = v;
        }
        s_thresh = a2 - 1.0f;   // margin >> bf16 dot-product error bound (~0.1)
    }
    __syncthreads();
    const float thresh = s_thresh;

    // Phase B: gather all candidates within margin of approx top-2
    for (int e = tid; e < NC; e += 256) {
        if (cands[e].v >= thresh) {
            int k = atomicAdd(&cnt, 1);
            if (k < 128) qidx[k] = cands[e].idx;
        }
    }
    __syncthreads();
    const int n = cnt < 128 ? cnt : 128;

    // Phase C: exact double dot for each qualifying candidate (one wave each)
    for (int c = wv; c < n; c += 4) {
        unsigned idx = qidx[c];
        unsigned gi = idx >> 13;       // / 8192
        unsigned gj = idx & 8191;
        const float* pa = x + (size_t)gi * DD;
        const float* pb = x + (size_t)gj * DD;
        double s = (double)pa[lane] * (double)pb[lane]
                 + (double)pa[lane + 64] * (double)pb[lane + 64];
        #pragma unroll
        for (int off = 32; off >= 1; off >>= 1) s += __shfl_down(s, off);
        if (lane == 0) qex[c] = s;
    }
    __syncthreads();

    // Phase D: exact top-2 over rechecked candidates
    if (tid == 0) {
        double d1 = -DBL_MAX, d2 = -DBL_MAX;
        unsigned bi = 0;
        for (int c = 0; c < n; ++c) {
            double v = qex[c];
            if (v > d1) { d2 = d1; d1 = v; bi = qidx[c]; }
            else if (v > d2) d2 = v;
        }
        sd1 = d1; sd2 = d2; stopi = bi;
    }
    __syncthreads();

    const double top1 = sd1, top2 = sd2;
    const unsigned topi = stopi;

    // Phase E: mean(sim_oth / sim_self)
    double acc = 0.0;
    for (int p = tid; p < PP; p += 256) {
        unsigned selfidx = (unsigned)(p * NN + p + 1);
        double so = (topi == selfidx) ? top2 : top1;
        acc += so / ss[p];
    }
    sacc[tid] = acc;
    __syncthreads();
    for (int s = 128; s >= 1; s >>= 1) {
        if (tid < s) sacc[tid] += sacc[tid + s];
        __syncthreads();
    }
    if (tid == 0) out[0] = (float)(sacc[0] / (double)PP);
}

extern "C" void kernel_launch(void* const* d_in, const int* in_sizes, int n_in,
                              void* d_out, int out_size, void* d_ws, size_t ws_size,
                              hipStream_t stream) {
    (void)in_sizes; (void)n_in; (void)out_size; (void)ws_size;
    const float* x = (const float*)d_in[0];
    float* out = (float*)d_out;

    double* ss  = (double*)d_ws;                                  // 32 KB
    Cand* cands = (Cand*)((char*)d_ws + PP * sizeof(double));     // ~33 KB
    unsigned short* xb = (unsigned short*)((char*)d_ws + 131072); // 2 MB bf16 copy

    k_prep<<<320, 256, 0, stream>>>(x, xb, ss);
    k_top2<<<NBLK, 256, 0, stream>>>(xb, cands);
    k_final<<<1, 256, 0, stream>>>(x, ss, cands, out);
}